// Round 1
// baseline (385.461 us; speedup 1.0000x reference)
//
#include <hip/hip_runtime.h>

typedef short bf16x8 __attribute__((ext_vector_type(8)));
typedef float f32x4 __attribute__((ext_vector_type(4)));

__device__ __forceinline__ unsigned short f2bf(float f) {
  unsigned int u = __float_as_uint(f);
  u = (u + 0x7FFFu + ((u >> 16) & 1u)) >> 16;  // RNE, finite data
  return (unsigned short)u;
}

__device__ __forceinline__ float silu_f(float v) {
  return v * (1.0f / (1.0f + __expf(-v)));
}

// ---------------------------------------------------------------------------
// Weight prep: bf16 conversion + per-lane fragment swizzle.
// B1 (layer1, K padded 16->32, row k==16 holds rb1 so bias comes free):
//   idx = (nt*64+lane)*8+j  -> value at k=(lane>>4)*8+j, n=nt*16+(lane&15)
// B2/D0/D1/D2 (K=128):
//   idx = ((nt*4+kc)*64+lane)*8+j -> k=kc*32+(lane>>4)*8+j, n=nt*16+(lane&15)
// ---------------------------------------------------------------------------
__global__ void k_prep(const float* __restrict__ rW1, const float* __restrict__ rb1,
                       const float* __restrict__ rW2, const float* __restrict__ dW0,
                       const float* __restrict__ dW1, const float* __restrict__ dW2,
                       unsigned short* __restrict__ wb) {
  int i = blockIdx.x * blockDim.x + threadIdx.x;
  if (i < 4096) {
    int j = i & 7, lane = (i >> 3) & 63, nt = i >> 9;
    int k = (lane >> 4) * 8 + j, n = nt * 16 + (lane & 15);
    float v = (k < 16) ? rW1[k * 128 + n] : (k == 16 ? rb1[n] : 0.0f);
    wb[i] = f2bf(v);
  } else if (i < 4096 + 4 * 16384) {
    int i2 = i - 4096, buf = i2 >> 14, r = i2 & 16383;
    int j = r & 7, lane = (r >> 3) & 63, g = r >> 9, kc = g & 3, nt = g >> 2;
    int k = kc * 32 + (lane >> 4) * 8 + j, n = nt * 16 + (lane & 15);
    const float* W = (buf == 0) ? rW2 : (buf == 1) ? dW0 : (buf == 2) ? dW1 : dW2;
    wb[4096 + buf * 16384 + r] = f2bf(W[k * 128 + n]);
  }
}

// ---------------------------------------------------------------------------
// Fused edge kernel: W = silu(rb@rW1+rb1)@rW2+rb2; atomicAdd(x[dst], h[src]*W)
// One wave = 16 edges. Layer1 MFMA (K=32 padded) -> silu -> swizzled LDS ->
// layer2 MFMA with rW2 resident in 128 VGPRs -> gather/scatter epilogue.
// ---------------------------------------------------------------------------
__global__ __launch_bounds__(256, 2) void k_edge(
    const float* __restrict__ rb, const int* __restrict__ ei,
    const float* __restrict__ h, const unsigned short* __restrict__ B1,
    const unsigned short* __restrict__ B2, const float* __restrict__ rb2,
    float* __restrict__ x, int E, int ntiles) {
  const int lane = threadIdx.x & 63;
  const int wid = threadIdx.x >> 6;
  const int kg = lane >> 4;
  const int c15 = lane & 15;
  __shared__ unsigned short hid[64 * 128];  // bf16, XOR-swizzled

  bf16x8 b2f[8][4];
#pragma unroll
  for (int nt = 0; nt < 8; ++nt)
#pragma unroll
    for (int kc = 0; kc < 4; ++kc)
      b2f[nt][kc] = *(const bf16x8*)(B2 + (((nt * 4 + kc) * 64 + lane) << 3));

  float rb2r[8];
#pragma unroll
  for (int nt = 0; nt < 8; ++nt) rb2r[nt] = rb2[nt * 16 + c15];

  for (int t = blockIdx.x; t < ntiles; t += gridDim.x) {
    const int ebase = t * 64 + wid * 16;

    // ---- layer 1: A-frag straight from global rb (K 0..15 real, 16 = bias 1.0)
    bf16x8 a1 = {};
    if (kg < 2) {
      const int e = ebase + c15;
      if (e < E) {
        const float4 v0 = *(const float4*)(rb + (size_t)e * 16 + kg * 8);
        const float4 v1 = *(const float4*)(rb + (size_t)e * 16 + kg * 8 + 4);
        a1[0] = (short)f2bf(v0.x); a1[1] = (short)f2bf(v0.y);
        a1[2] = (short)f2bf(v0.z); a1[3] = (short)f2bf(v0.w);
        a1[4] = (short)f2bf(v1.x); a1[5] = (short)f2bf(v1.y);
        a1[6] = (short)f2bf(v1.z); a1[7] = (short)f2bf(v1.w);
      }
    } else if (kg == 2) {
      a1[0] = (short)0x3F80;  // bf16 1.0 at k==16 -> adds rb1 row of B1
    }

#pragma unroll
    for (int nt = 0; nt < 8; ++nt) {
      bf16x8 b1 = *(const bf16x8*)(B1 + ((nt * 64 + lane) << 3));
      f32x4 d1 = {};
      d1 = __builtin_amdgcn_mfma_f32_16x16x32_bf16(a1, b1, d1, 0, 0, 0);
#pragma unroll
      for (int r = 0; r < 4; ++r) {
        const int row = wid * 16 + kg * 4 + r;  // D: row=(lane>>4)*4+reg
        float v = silu_f(d1[r]);
        int byt = row * 256 + (nt * 16 + c15) * 2;
        byt ^= (row & 7) << 4;
        *(unsigned short*)((char*)hid + byt) = f2bf(v);
      }
    }

    // ---- layer 2: A from LDS (own wave's rows only; no barrier needed)
    const int arow = wid * 16 + c15;
    f32x4 acc[8] = {};
#pragma unroll
    for (int kc = 0; kc < 4; ++kc) {
      int byt = arow * 256 + (kc * 32 + kg * 8) * 2;
      byt ^= (arow & 7) << 4;
      const bf16x8 a2 = *(const bf16x8*)((const char*)hid + byt);
#pragma unroll
      for (int nt = 0; nt < 8; ++nt)
        acc[nt] = __builtin_amdgcn_mfma_f32_16x16x32_bf16(a2, b2f[nt][kc], acc[nt], 0, 0, 0);
    }

    // ---- epilogue: +rb2, gather h[src], scatter-add into x[dst]
#pragma unroll
    for (int r = 0; r < 4; ++r) {
      const int e = ebase + kg * 4 + r;
      if (e < E) {
        const int s = ei[e];
        const int d = ei[E + e];
#pragma unroll
        for (int nt = 0; nt < 8; ++nt) {
          const int col = nt * 16 + c15;
          const float w = acc[nt][r] + rb2r[nt];
          const float hv = h[(size_t)s * 128 + col];
          atomicAdd(x + (size_t)d * 128 + col, w * hv);
        }
      }
    }
  }
}

// ---------------------------------------------------------------------------
// Dense layer, in-place (row-diagonal): x = silu(x @ W + b)
// ---------------------------------------------------------------------------
__global__ __launch_bounds__(256, 2) void k_dense(
    float* __restrict__ x, const unsigned short* __restrict__ Bw,
    const float* __restrict__ bias, int M) {
  const int lane = threadIdx.x & 63;
  const int wid = threadIdx.x >> 6;
  const int kg = lane >> 4;
  const int c15 = lane & 15;

  bf16x8 bf[8][4];
#pragma unroll
  for (int nt = 0; nt < 8; ++nt)
#pragma unroll
    for (int kc = 0; kc < 4; ++kc)
      bf[nt][kc] = *(const bf16x8*)(Bw + (((nt * 4 + kc) * 64 + lane) << 3));

  float br[8];
#pragma unroll
  for (int nt = 0; nt < 8; ++nt) br[nt] = bias[nt * 16 + c15];

  const int tiles = (M + 63) >> 6;
  for (int t = blockIdx.x; t < tiles; t += gridDim.x) {
    const int rbase = t * 64 + wid * 16;
    const int row = rbase + c15;
    bf16x8 a[4];
#pragma unroll
    for (int kc = 0; kc < 4; ++kc) {
      bf16x8 az = {};
      if (row < M) {
        const float4 v0 = *(const float4*)(x + (size_t)row * 128 + kc * 32 + kg * 8);
        const float4 v1 = *(const float4*)(x + (size_t)row * 128 + kc * 32 + kg * 8 + 4);
        az[0] = (short)f2bf(v0.x); az[1] = (short)f2bf(v0.y);
        az[2] = (short)f2bf(v0.z); az[3] = (short)f2bf(v0.w);
        az[4] = (short)f2bf(v1.x); az[5] = (short)f2bf(v1.y);
        az[6] = (short)f2bf(v1.z); az[7] = (short)f2bf(v1.w);
      }
      a[kc] = az;
    }
    f32x4 acc[8] = {};
#pragma unroll
    for (int kc = 0; kc < 4; ++kc)
#pragma unroll
      for (int nt = 0; nt < 8; ++nt)
        acc[nt] = __builtin_amdgcn_mfma_f32_16x16x32_bf16(a[kc], bf[nt][kc], acc[nt], 0, 0, 0);
#pragma unroll
    for (int r = 0; r < 4; ++r) {
      const int orow = rbase + kg * 4 + r;
      if (orow < M) {
#pragma unroll
        for (int nt = 0; nt < 8; ++nt)
          x[(size_t)orow * 128 + nt * 16 + c15] = silu_f(acc[nt][r] + br[nt]);
      }
    }
  }
}

// ---------------------------------------------------------------------------
// Output layer: out[row] = dot(x[row,:128], oW) + ob   (wave per row)
// ---------------------------------------------------------------------------
__global__ void k_out(const float* __restrict__ x, const float* __restrict__ oW,
                      const float* __restrict__ ob, float* __restrict__ out, int M) {
  const int lane = threadIdx.x & 63;
  const int w = (int)((blockIdx.x * blockDim.x + threadIdx.x) >> 6);
  const int nw = (int)((gridDim.x * blockDim.x) >> 6);
  const float w0 = oW[lane], w1 = oW[64 + lane];
  const float obv = ob[0];
  for (int row = w; row < M; row += nw) {
    float a = x[(size_t)row * 128 + lane] * w0 + x[(size_t)row * 128 + 64 + lane] * w1;
#pragma unroll
    for (int m = 32; m; m >>= 1) a += __shfl_xor(a, m);
    if (lane == 0) out[row] = a + obv;
  }
}

// ---------------------------------------------------------------------------
extern "C" void kernel_launch(void* const* d_in, const int* in_sizes, int n_in,
                              void* d_out, int out_size, void* d_ws, size_t ws_size,
                              hipStream_t stream) {
  const float* h   = (const float*)d_in[0];
  const float* rb  = (const float*)d_in[1];
  const int*   ei  = (const int*)d_in[2];
  const float* rW1 = (const float*)d_in[3];
  const float* rb1 = (const float*)d_in[4];
  const float* rW2 = (const float*)d_in[5];
  const float* rb2 = (const float*)d_in[6];
  const float* dW0 = (const float*)d_in[7];
  const float* db0 = (const float*)d_in[8];
  const float* dW1 = (const float*)d_in[9];
  const float* db1 = (const float*)d_in[10];
  const float* dW2 = (const float*)d_in[11];
  const float* db2 = (const float*)d_in[12];
  const float* oW  = (const float*)d_in[13];
  const float* ob  = (const float*)d_in[14];

  const int NN = in_sizes[0] / 128;  // 50000 nodes
  const int E  = in_sizes[1] / 16;   // 600000 edges
  const size_t xbytes = (size_t)NN * 128 * sizeof(float);

  float* x = (float*)d_ws;
  unsigned short* wb = (unsigned short*)((char*)d_ws + ((xbytes + 255) & ~(size_t)255));
  // wb layout (ushorts): B1 @0 (4096), B2 @4096, D0 @20480, D1 @36864, D2 @53248

  hipMemsetAsync(x, 0, xbytes, stream);
  k_prep<<<(69632 + 255) / 256, 256, 0, stream>>>(rW1, rb1, rW2, dW0, dW1, dW2, wb);

  const int ntiles = (E + 63) / 64;
  const int eg = ntiles < 1024 ? ntiles : 1024;
  k_edge<<<eg, 256, 0, stream>>>(rb, ei, h, wb, wb + 4096, rb2, x, E, ntiles);

  k_dense<<<512, 256, 0, stream>>>(x, wb + 20480, db0, NN);
  k_dense<<<512, 256, 0, stream>>>(x, wb + 36864, db1, NN);
  k_dense<<<512, 256, 0, stream>>>(x, wb + 53248, db2, NN);
  k_out<<<512, 256, 0, stream>>>(x, oW, ob, (float*)d_out, NN);
}

// Round 2
// 358.685 us; speedup vs baseline: 1.0747x; 1.0747x over previous
//
#include <hip/hip_runtime.h>

typedef short bf16x8 __attribute__((ext_vector_type(8)));
typedef float f32x4 __attribute__((ext_vector_type(4)));

__device__ __forceinline__ unsigned short f2bf(float f) {
  unsigned int u = __float_as_uint(f);
  u = (u + 0x7FFFu + ((u >> 16) & 1u)) >> 16;  // RNE, finite data
  return (unsigned short)u;
}
__device__ __forceinline__ float bf2f(unsigned short u) {
  return __uint_as_float(((unsigned int)u) << 16);
}
__device__ __forceinline__ float silu_f(float v) {
  return v * (1.0f / (1.0f + __expf(-v)));
}

// ---------------------------------------------------------------------------
// Weight prep: bf16 conversion + per-lane fragment swizzle.
// B1 (layer1, K padded 16->32, row k==16 holds rb1 so bias comes free):
//   idx = (nt*64+lane)*8+j  -> value at k=(lane>>4)*8+j, n=nt*16+(lane&15)
// B2/D0/D1/D2 (K=128):
//   idx = ((nt*4+kc)*64+lane)*8+j -> k=kc*32+(lane>>4)*8+j, n=nt*16+(lane&15)
// ---------------------------------------------------------------------------
__global__ void k_prep(const float* __restrict__ rW1, const float* __restrict__ rb1,
                       const float* __restrict__ rW2, const float* __restrict__ dW0,
                       const float* __restrict__ dW1, const float* __restrict__ dW2,
                       unsigned short* __restrict__ wb) {
  int i = blockIdx.x * blockDim.x + threadIdx.x;
  if (i < 4096) {
    int j = i & 7, lane = (i >> 3) & 63, nt = i >> 9;
    int k = (lane >> 4) * 8 + j, n = nt * 16 + (lane & 15);
    float v = (k < 16) ? rW1[k * 128 + n] : (k == 16 ? rb1[n] : 0.0f);
    wb[i] = f2bf(v);
  } else if (i < 4096 + 4 * 16384) {
    int i2 = i - 4096, buf = i2 >> 14, r = i2 & 16383;
    int j = r & 7, lane = (r >> 3) & 63, g = r >> 9, kc = g & 3, nt = g >> 2;
    int k = kc * 32 + (lane >> 4) * 8 + j, n = nt * 16 + (lane & 15);
    const float* W = (buf == 0) ? rW2 : (buf == 1) ? dW0 : (buf == 2) ? dW1 : dW2;
    wb[4096 + buf * 16384 + r] = f2bf(W[k * 128 + n]);
  }
}

// --------------------------- CSR construction ------------------------------
__global__ void k_hist(const int* __restrict__ ei, int* __restrict__ hist, int E) {
  int e = blockIdx.x * blockDim.x + threadIdx.x;
  if (e < E) atomicAdd(&hist[ei[E + e]], 1);
}

// Single-block exclusive scan of hist[N] -> row_start[N+1], copy into bump[].
__global__ void k_scan(const int* __restrict__ hist, int* __restrict__ row_start,
                       int* __restrict__ bump, int N) {
  __shared__ int part[1024];
  const int t = threadIdx.x;
  const int ch = (N + 1023) >> 10;
  const int c0 = t * ch;
  const int c1 = min(c0 + ch, N);
  int s = 0;
  for (int i = c0; i < c1; ++i) s += hist[i];
  part[t] = s;
  __syncthreads();
  for (int off = 1; off < 1024; off <<= 1) {
    int v = (t >= off) ? part[t - off] : 0;
    __syncthreads();
    part[t] += v;
    __syncthreads();
  }
  int run = part[t] - s;  // exclusive prefix
  for (int i = c0; i < c1; ++i) {
    row_start[i] = run;
    bump[i] = run;
    run += hist[i];
  }
  if (t == 1023) row_start[N] = part[1023];
}

__global__ void k_pos(const int* __restrict__ ei, int* __restrict__ bump,
                      int* __restrict__ pos, int E) {
  int e = blockIdx.x * blockDim.x + threadIdx.x;
  if (e < E) pos[e] = atomicAdd(&bump[ei[E + e]], 1);
}

// ---------------------------------------------------------------------------
// Phase A: edge MLP + message formation, scatter-free.
// msg[e] = (silu(rb@rW1+rb1)@rW2 + rb2) * h[src[e]]  -> Mbuf[pos[e]] (bf16)
// One wave = 16 edges. Epilogue repacks via LDS so h reads are float4-chunked.
// ---------------------------------------------------------------------------
__global__ __launch_bounds__(256, 2) void k_edge2(
    const float* __restrict__ rb, const int* __restrict__ ei,
    const float* __restrict__ h, const unsigned short* __restrict__ B1,
    const unsigned short* __restrict__ B2, const float* __restrict__ rb2,
    const int* __restrict__ pos, unsigned short* __restrict__ Mbuf,
    int E, int ntiles) {
  const int lane = threadIdx.x & 63;
  const int wid = threadIdx.x >> 6;
  const int kg = lane >> 4;
  const int c15 = lane & 15;
  __shared__ __align__(16) unsigned short hid[64 * 128];  // bf16, XOR-swizzled

  bf16x8 b2f[8][4];
#pragma unroll
  for (int nt = 0; nt < 8; ++nt)
#pragma unroll
    for (int kc = 0; kc < 4; ++kc)
      b2f[nt][kc] = *(const bf16x8*)(B2 + (((nt * 4 + kc) * 64 + lane) << 3));

  float rb2r[8];
#pragma unroll
  for (int nt = 0; nt < 8; ++nt) rb2r[nt] = rb2[nt * 16 + c15];

  for (int t = blockIdx.x; t < ntiles; t += gridDim.x) {
    const int ebase = t * 64 + wid * 16;

    // ---- layer 1 A-frag from global rb (K 0..15 real, 16 = bias 1.0)
    bf16x8 a1 = {};
    if (kg < 2) {
      const int e = ebase + c15;
      if (e < E) {
        const float4 v0 = *(const float4*)(rb + (size_t)e * 16 + kg * 8);
        const float4 v1 = *(const float4*)(rb + (size_t)e * 16 + kg * 8 + 4);
        a1[0] = (short)f2bf(v0.x); a1[1] = (short)f2bf(v0.y);
        a1[2] = (short)f2bf(v0.z); a1[3] = (short)f2bf(v0.w);
        a1[4] = (short)f2bf(v1.x); a1[5] = (short)f2bf(v1.y);
        a1[6] = (short)f2bf(v1.z); a1[7] = (short)f2bf(v1.w);
      }
    } else if (kg == 2) {
      a1[0] = (short)0x3F80;  // bf16 1.0 at k==16 -> adds rb1 row of B1
    }

#pragma unroll
    for (int nt = 0; nt < 8; ++nt) {
      bf16x8 b1 = *(const bf16x8*)(B1 + ((nt * 64 + lane) << 3));
      f32x4 d1 = {};
      d1 = __builtin_amdgcn_mfma_f32_16x16x32_bf16(a1, b1, d1, 0, 0, 0);
#pragma unroll
      for (int r = 0; r < 4; ++r) {
        const int row = wid * 16 + kg * 4 + r;  // D: row=(lane>>4)*4+reg
        float v = silu_f(d1[r]);
        int byt = row * 256 + (nt * 16 + c15) * 2;
        byt ^= (row & 7) << 4;
        *(unsigned short*)((char*)hid + byt) = f2bf(v);
      }
    }

    // ---- layer 2: A from LDS (own wave's rows only; no barrier needed)
    const int arow = wid * 16 + c15;
    f32x4 acc[8] = {};
#pragma unroll
    for (int kc = 0; kc < 4; ++kc) {
      int byt = arow * 256 + (kc * 32 + kg * 8) * 2;
      byt ^= (arow & 7) << 4;
      const bf16x8 a2 = *(const bf16x8*)((const char*)hid + byt);
#pragma unroll
      for (int nt = 0; nt < 8; ++nt)
        acc[nt] = __builtin_amdgcn_mfma_f32_16x16x32_bf16(a2, b2f[nt][kc], acc[nt], 0, 0, 0);
    }

    // ---- W+rb2 back to LDS (bf16, same swizzle; own rows, no barrier)
#pragma unroll
    for (int nt = 0; nt < 8; ++nt)
#pragma unroll
      for (int r = 0; r < 4; ++r) {
        const int row = wid * 16 + kg * 4 + r;
        int byt = row * 256 + (nt * 16 + c15) * 2;
        byt ^= (row & 7) << 4;
        *(unsigned short*)((char*)hid + byt) = f2bf(acc[nt][r] + rb2r[nt]);
      }

    // ---- repack: 8 lanes/row, gather h in float4s, write 256B msg rows
#pragma unroll
    for (int pass = 0; pass < 2; ++pass) {
      const int ro = wid * 16 + pass * 8 + (lane >> 3);  // block-local row
      const int e = t * 64 + ro;
      if (e < E) {
        const int p = pos[e];
        const int s = ei[e];
        const int cg = (lane & 7) * 16;  // 16 cols per lane
        const int swz = (ro & 7) << 4;
        const int bas = ro * 256 + cg * 2;
        const bf16x8 w0 = *(const bf16x8*)((const char*)hid + (bas ^ swz));
        const bf16x8 w1 = *(const bf16x8*)((const char*)hid + ((bas + 16) ^ swz));
        const float4* hp = (const float4*)(h + (size_t)s * 128 + cg);
        const float4 h0 = hp[0], h1 = hp[1], h2 = hp[2], h3 = hp[3];
        bf16x8 m0, m1;
        m0[0] = (short)f2bf(bf2f((unsigned short)w0[0]) * h0.x);
        m0[1] = (short)f2bf(bf2f((unsigned short)w0[1]) * h0.y);
        m0[2] = (short)f2bf(bf2f((unsigned short)w0[2]) * h0.z);
        m0[3] = (short)f2bf(bf2f((unsigned short)w0[3]) * h0.w);
        m0[4] = (short)f2bf(bf2f((unsigned short)w0[4]) * h1.x);
        m0[5] = (short)f2bf(bf2f((unsigned short)w0[5]) * h1.y);
        m0[6] = (short)f2bf(bf2f((unsigned short)w0[6]) * h1.z);
        m0[7] = (short)f2bf(bf2f((unsigned short)w0[7]) * h1.w);
        m1[0] = (short)f2bf(bf2f((unsigned short)w1[0]) * h2.x);
        m1[1] = (short)f2bf(bf2f((unsigned short)w1[1]) * h2.y);
        m1[2] = (short)f2bf(bf2f((unsigned short)w1[2]) * h2.z);
        m1[3] = (short)f2bf(bf2f((unsigned short)w1[3]) * h2.w);
        m1[4] = (short)f2bf(bf2f((unsigned short)w1[4]) * h3.x);
        m1[5] = (short)f2bf(bf2f((unsigned short)w1[5]) * h3.y);
        m1[6] = (short)f2bf(bf2f((unsigned short)w1[6]) * h3.z);
        m1[7] = (short)f2bf(bf2f((unsigned short)w1[7]) * h3.w);
        *(bf16x8*)(Mbuf + (size_t)p * 128 + cg) = m0;
        *(bf16x8*)(Mbuf + (size_t)p * 128 + cg + 8) = m1;
      }
    }
  }
}

// ---------------------------------------------------------------------------
// Phase B: x[n] = sum of contiguous Mbuf rows [row_start[n], row_start[n+1])
// Wave per node; lane owns 2 cols. Pure streaming reads.
// ---------------------------------------------------------------------------
__global__ __launch_bounds__(256) void k_gather(
    const unsigned short* __restrict__ Mbuf, const int* __restrict__ row_start,
    float* __restrict__ x, int NN) {
  const int lane = threadIdx.x & 63;
  const int w = (int)((blockIdx.x * blockDim.x + threadIdx.x) >> 6);
  const int nw = (int)((gridDim.x * blockDim.x) >> 6);
  for (int n = w; n < NN; n += nw) {
    const int b0 = row_start[n], b1 = row_start[n + 1];
    float a0 = 0.f, a1 = 0.f, c0 = 0.f, c1 = 0.f;
    int i = b0;
    for (; i + 1 < b1; i += 2) {
      const unsigned int v0 = *(const unsigned int*)(Mbuf + (size_t)i * 128 + lane * 2);
      const unsigned int v1 = *(const unsigned int*)(Mbuf + (size_t)(i + 1) * 128 + lane * 2);
      a0 += __uint_as_float(v0 << 16);
      a1 += __uint_as_float(v0 & 0xffff0000u);
      c0 += __uint_as_float(v1 << 16);
      c1 += __uint_as_float(v1 & 0xffff0000u);
    }
    if (i < b1) {
      const unsigned int v0 = *(const unsigned int*)(Mbuf + (size_t)i * 128 + lane * 2);
      a0 += __uint_as_float(v0 << 16);
      a1 += __uint_as_float(v0 & 0xffff0000u);
    }
    float2 r;
    r.x = a0 + c0;
    r.y = a1 + c1;
    *(float2*)(x + (size_t)n * 128 + lane * 2) = r;
  }
}

// ---------------------------------------------------------------------------
// Fallback fused edge kernel (round-1 atomic version, used if ws too small)
// ---------------------------------------------------------------------------
__global__ __launch_bounds__(256, 2) void k_edge(
    const float* __restrict__ rb, const int* __restrict__ ei,
    const float* __restrict__ h, const unsigned short* __restrict__ B1,
    const unsigned short* __restrict__ B2, const float* __restrict__ rb2,
    float* __restrict__ x, int E, int ntiles) {
  const int lane = threadIdx.x & 63;
  const int wid = threadIdx.x >> 6;
  const int kg = lane >> 4;
  const int c15 = lane & 15;
  __shared__ __align__(16) unsigned short hid[64 * 128];

  bf16x8 b2f[8][4];
#pragma unroll
  for (int nt = 0; nt < 8; ++nt)
#pragma unroll
    for (int kc = 0; kc < 4; ++kc)
      b2f[nt][kc] = *(const bf16x8*)(B2 + (((nt * 4 + kc) * 64 + lane) << 3));

  float rb2r[8];
#pragma unroll
  for (int nt = 0; nt < 8; ++nt) rb2r[nt] = rb2[nt * 16 + c15];

  for (int t = blockIdx.x; t < ntiles; t += gridDim.x) {
    const int ebase = t * 64 + wid * 16;
    bf16x8 a1 = {};
    if (kg < 2) {
      const int e = ebase + c15;
      if (e < E) {
        const float4 v0 = *(const float4*)(rb + (size_t)e * 16 + kg * 8);
        const float4 v1 = *(const float4*)(rb + (size_t)e * 16 + kg * 8 + 4);
        a1[0] = (short)f2bf(v0.x); a1[1] = (short)f2bf(v0.y);
        a1[2] = (short)f2bf(v0.z); a1[3] = (short)f2bf(v0.w);
        a1[4] = (short)f2bf(v1.x); a1[5] = (short)f2bf(v1.y);
        a1[6] = (short)f2bf(v1.z); a1[7] = (short)f2bf(v1.w);
      }
    } else if (kg == 2) {
      a1[0] = (short)0x3F80;
    }
#pragma unroll
    for (int nt = 0; nt < 8; ++nt) {
      bf16x8 b1 = *(const bf16x8*)(B1 + ((nt * 64 + lane) << 3));
      f32x4 d1 = {};
      d1 = __builtin_amdgcn_mfma_f32_16x16x32_bf16(a1, b1, d1, 0, 0, 0);
#pragma unroll
      for (int r = 0; r < 4; ++r) {
        const int row = wid * 16 + kg * 4 + r;
        float v = silu_f(d1[r]);
        int byt = row * 256 + (nt * 16 + c15) * 2;
        byt ^= (row & 7) << 4;
        *(unsigned short*)((char*)hid + byt) = f2bf(v);
      }
    }
    const int arow = wid * 16 + c15;
    f32x4 acc[8] = {};
#pragma unroll
    for (int kc = 0; kc < 4; ++kc) {
      int byt = arow * 256 + (kc * 32 + kg * 8) * 2;
      byt ^= (arow & 7) << 4;
      const bf16x8 a2 = *(const bf16x8*)((const char*)hid + byt);
#pragma unroll
      for (int nt = 0; nt < 8; ++nt)
        acc[nt] = __builtin_amdgcn_mfma_f32_16x16x32_bf16(a2, b2f[nt][kc], acc[nt], 0, 0, 0);
    }
#pragma unroll
    for (int r = 0; r < 4; ++r) {
      const int e = ebase + kg * 4 + r;
      if (e < E) {
        const int s = ei[e];
        const int d = ei[E + e];
#pragma unroll
        for (int nt = 0; nt < 8; ++nt) {
          const int col = nt * 16 + c15;
          const float w = acc[nt][r] + rb2r[nt];
          const float hv = h[(size_t)s * 128 + col];
          atomicAdd(x + (size_t)d * 128 + col, w * hv);
        }
      }
    }
  }
}

// ---------------------------------------------------------------------------
// Dense layer, in-place (row-diagonal): x = silu(x @ W + b)
// ---------------------------------------------------------------------------
__global__ __launch_bounds__(256, 2) void k_dense(
    float* __restrict__ x, const unsigned short* __restrict__ Bw,
    const float* __restrict__ bias, int M) {
  const int lane = threadIdx.x & 63;
  const int wid = threadIdx.x >> 6;
  const int kg = lane >> 4;
  const int c15 = lane & 15;

  bf16x8 bf[8][4];
#pragma unroll
  for (int nt = 0; nt < 8; ++nt)
#pragma unroll
    for (int kc = 0; kc < 4; ++kc)
      bf[nt][kc] = *(const bf16x8*)(Bw + (((nt * 4 + kc) * 64 + lane) << 3));

  float br[8];
#pragma unroll
  for (int nt = 0; nt < 8; ++nt) br[nt] = bias[nt * 16 + c15];

  const int tiles = (M + 63) >> 6;
  for (int t = blockIdx.x; t < tiles; t += gridDim.x) {
    const int rbase = t * 64 + wid * 16;
    const int row = rbase + c15;
    bf16x8 a[4];
#pragma unroll
    for (int kc = 0; kc < 4; ++kc) {
      bf16x8 az = {};
      if (row < M) {
        const float4 v0 = *(const float4*)(x + (size_t)row * 128 + kc * 32 + kg * 8);
        const float4 v1 = *(const float4*)(x + (size_t)row * 128 + kc * 32 + kg * 8 + 4);
        az[0] = (short)f2bf(v0.x); az[1] = (short)f2bf(v0.y);
        az[2] = (short)f2bf(v0.z); az[3] = (short)f2bf(v0.w);
        az[4] = (short)f2bf(v1.x); az[5] = (short)f2bf(v1.y);
        az[6] = (short)f2bf(v1.z); az[7] = (short)f2bf(v1.w);
      }
      a[kc] = az;
    }
    f32x4 acc[8] = {};
#pragma unroll
    for (int kc = 0; kc < 4; ++kc)
#pragma unroll
      for (int nt = 0; nt < 8; ++nt)
        acc[nt] = __builtin_amdgcn_mfma_f32_16x16x32_bf16(a[kc], bf[nt][kc], acc[nt], 0, 0, 0);
#pragma unroll
    for (int r = 0; r < 4; ++r) {
      const int orow = rbase + kg * 4 + r;
      if (orow < M) {
#pragma unroll
        for (int nt = 0; nt < 8; ++nt)
          x[(size_t)orow * 128 + nt * 16 + c15] = silu_f(acc[nt][r] + br[nt]);
      }
    }
  }
}

// ---------------------------------------------------------------------------
// Output layer: out[row] = dot(x[row,:128], oW) + ob   (wave per row)
// ---------------------------------------------------------------------------
__global__ void k_out(const float* __restrict__ x, const float* __restrict__ oW,
                      const float* __restrict__ ob, float* __restrict__ out, int M) {
  const int lane = threadIdx.x & 63;
  const int w = (int)((blockIdx.x * blockDim.x + threadIdx.x) >> 6);
  const int nw = (int)((gridDim.x * blockDim.x) >> 6);
  const float w0 = oW[lane], w1 = oW[64 + lane];
  const float obv = ob[0];
  for (int row = w; row < M; row += nw) {
    float a = x[(size_t)row * 128 + lane] * w0 + x[(size_t)row * 128 + 64 + lane] * w1;
#pragma unroll
    for (int m = 32; m; m >>= 1) a += __shfl_xor(a, m);
    if (lane == 0) out[row] = a + obv;
  }
}

// ---------------------------------------------------------------------------
extern "C" void kernel_launch(void* const* d_in, const int* in_sizes, int n_in,
                              void* d_out, int out_size, void* d_ws, size_t ws_size,
                              hipStream_t stream) {
  const float* h   = (const float*)d_in[0];
  const float* rb  = (const float*)d_in[1];
  const int*   ei  = (const int*)d_in[2];
  const float* rW1 = (const float*)d_in[3];
  const float* rb1 = (const float*)d_in[4];
  const float* rW2 = (const float*)d_in[5];
  const float* rb2 = (const float*)d_in[6];
  const float* dW0 = (const float*)d_in[7];
  const float* db0 = (const float*)d_in[8];
  const float* dW1 = (const float*)d_in[9];
  const float* db1 = (const float*)d_in[10];
  const float* dW2 = (const float*)d_in[11];
  const float* db2 = (const float*)d_in[12];
  const float* oW  = (const float*)d_in[13];
  const float* ob  = (const float*)d_in[14];

  const int NN = in_sizes[0] / 128;  // 50000 nodes
  const int E  = in_sizes[1] / 16;   // 600000 edges

  char* base = (char*)d_ws;
  size_t off = 0;
  auto alloc = [&](size_t bytes) {
    char* p = base + off;
    off += (bytes + 255) & ~(size_t)255;
    return p;
  };
  float* x            = (float*)alloc((size_t)NN * 128 * 4);
  unsigned short* wb  = (unsigned short*)alloc((size_t)69632 * 2);
  int* row_start      = (int*)alloc((size_t)(NN + 1) * 4);
  int* hist           = (int*)alloc((size_t)NN * 4);
  int* bump           = (int*)alloc((size_t)NN * 4);
  int* pos            = (int*)alloc((size_t)E * 4);
  unsigned short* Mb  = (unsigned short*)alloc((size_t)E * 256);
  const bool fits = off <= ws_size;

  k_prep<<<(69632 + 255) / 256, 256, 0, stream>>>(rW1, rb1, rW2, dW0, dW1, dW2, wb);

  const int ntiles = (E + 63) / 64;
  const int gE = (E + 255) / 256;

  if (fits) {
    hipMemsetAsync(hist, 0, (size_t)NN * 4, stream);
    k_hist<<<gE, 256, 0, stream>>>(ei, hist, E);
    k_scan<<<1, 1024, 0, stream>>>(hist, row_start, bump, NN);
    k_pos<<<gE, 256, 0, stream>>>(ei, bump, pos, E);
    const int eg = ntiles < 2048 ? ntiles : 2048;
    k_edge2<<<eg, 256, 0, stream>>>(rb, ei, h, wb, wb + 4096, rb2, pos, Mb, E, ntiles);
    const int gg = (NN + 3) / 4;
    k_gather<<<(gg < 12500 ? gg : 12500), 256, 0, stream>>>(Mb, row_start, x, NN);
  } else {
    hipMemsetAsync(x, 0, (size_t)NN * 512, stream);
    const int eg = ntiles < 1024 ? ntiles : 1024;
    k_edge<<<eg, 256, 0, stream>>>(rb, ei, h, wb, wb + 4096, rb2, x, E, ntiles);
  }

  k_dense<<<512, 256, 0, stream>>>(x, wb + 20480, db0, NN);
  k_dense<<<512, 256, 0, stream>>>(x, wb + 36864, db1, NN);
  k_dense<<<512, 256, 0, stream>>>(x, wb + 53248, db2, NN);
  k_out<<<512, 256, 0, stream>>>(x, oW, ob, (float*)d_out, NN);
}